// Round 1
// baseline (203.400 us; speedup 1.0000x reference)
//
#include <hip/hip_runtime.h>
#include <hip/hip_bf16.h>

// ContrastiveLoss: loss = mean_i [ logsumexp_j(logits[i,:]) - pos_sim[i,i] ]
// logits = [20*xn@tn^T | 20*xn@hn^T + I] , xn/tn/hn row-normalized.
// Strategy: normalize->bf16, fused bf16-MFMA GEMM (4096x8192x1024) with
// exp-sum epilogue (fixed bias 21 >= max logit, so no online max needed),
// then tiny finalize reduction.

#define AS1 __attribute__((address_space(1)))
#define AS3 __attribute__((address_space(3)))

constexpr int N = 4096;
constexpr int D = 1024;
constexpr float TEMP_INV = 20.0f;   // 1/0.05
constexpr float CBIAS = 21.0f;      // >= max possible logit (20*1 + 1)

typedef float f32x4 __attribute__((ext_vector_type(4)));
typedef short bf16x8 __attribute__((ext_vector_type(8)));

static __device__ __forceinline__ unsigned short f2bf(float f) {
    __hip_bfloat16 h = __float2bfloat16(f);  // RNE
    union { __hip_bfloat16 h; unsigned short u; } cv;
    cv.h = h;
    return cv.u;
}

// One block per row (3*N blocks). 256 threads, 4 floats each (D=1024).
__global__ __launch_bounds__(256) void normalize_kernel(
    const float* __restrict__ in0, const float* __restrict__ in1,
    const float* __restrict__ in2, unsigned short* __restrict__ Abuf,
    unsigned short* __restrict__ Bbuf) {
    const int b = blockIdx.x;
    const int mat = b >> 12;       // 0: input, 1: target, 2: hard_negative
    const int row = b & (N - 1);
    const float* src = (mat == 0) ? in0 : (mat == 1) ? in1 : in2;
    unsigned short* dst = (mat == 0) ? (Abuf + (size_t)row * D)
                        : (mat == 1) ? (Bbuf + (size_t)row * D)
                                     : (Bbuf + (size_t)(row + N) * D);
    const int t = threadIdx.x;
    const float4* s4 = (const float4*)(src + (size_t)row * D);
    float4 v = s4[t];
    float p = v.x * v.x + v.y * v.y + v.z * v.z + v.w * v.w;
    for (int m = 32; m; m >>= 1) p += __shfl_down(p, m);  // 64-lane reduce
    __shared__ float red[4];
    const int lane = t & 63, wave = t >> 6;
    if (lane == 0) red[wave] = p;
    __syncthreads();
    const float sumsq = red[0] + red[1] + red[2] + red[3];
    const float inv = 1.0f / fmaxf(sqrtf(sumsq), 1e-8f);
    ushort4 o;
    o.x = f2bf(v.x * inv);
    o.y = f2bf(v.y * inv);
    o.z = f2bf(v.z * inv);
    o.w = f2bf(v.w * inv);
    ((ushort4*)dst)[t] = o;
}

// 128x128 tile, BK=32, 4 waves in 2x2, each wave 64x64 via 4x4 of 16x16x32.
// A: [N, D] bf16 row-major (xn). B: [2N, D] bf16 row-major (tn;hn).
// C[i,j] = dot(A_i, B_j). Epilogue: e = exp(20*c + diagw - 21), row-reduce.
__global__ __launch_bounds__(256) void gemm_lse_kernel(
    const unsigned short* __restrict__ A, const unsigned short* __restrict__ B,
    float* __restrict__ rowsum, float* __restrict__ posdiag) {
    __shared__ __align__(16) short As[128 * 32];
    __shared__ __align__(16) short Bs[128 * 32];

    const int tid = threadIdx.x;
    const int lane = tid & 63;
    const int wave = tid >> 6;
    const int wr = wave >> 1, wc = wave & 1;
    const int quad = lane >> 4, colid = lane & 15;
    const int rowBase = blockIdx.y * 128;
    const int colBase = blockIdx.x * 128;

    f32x4 acc[4][4];
#pragma unroll
    for (int i = 0; i < 4; ++i)
#pragma unroll
        for (int j = 0; j < 4; ++j) acc[i][j] = {0.f, 0.f, 0.f, 0.f};

    // Staging chunk ids: chunk c covers (row=c>>2, k8=(c&3)*8), 16B each.
    const int cA0 = tid, cA1 = tid + 256;  // 512 chunks per 128x32 tile

    for (int kb = 0; kb < D / 32; ++kb) {
        const int k0 = kb * 32;
        __syncthreads();  // prior reads done before overwrite
        {
            const unsigned short* g0 =
                A + ((size_t)(rowBase + (cA0 >> 2)) * D + k0 + (cA0 & 3) * 8);
            __builtin_amdgcn_global_load_lds((const AS1 void*)g0,
                (AS3 void*)(As + wave * 512), 16, 0, 0);
            const unsigned short* g1 =
                A + ((size_t)(rowBase + (cA1 >> 2)) * D + k0 + (cA1 & 3) * 8);
            __builtin_amdgcn_global_load_lds((const AS1 void*)g1,
                (AS3 void*)(As + 2048 + wave * 512), 16, 0, 0);
            const unsigned short* g2 =
                B + ((size_t)(colBase + (cA0 >> 2)) * D + k0 + (cA0 & 3) * 8);
            __builtin_amdgcn_global_load_lds((const AS1 void*)g2,
                (AS3 void*)(Bs + wave * 512), 16, 0, 0);
            const unsigned short* g3 =
                B + ((size_t)(colBase + (cA1 >> 2)) * D + k0 + (cA1 & 3) * 8);
            __builtin_amdgcn_global_load_lds((const AS1 void*)g3,
                (AS3 void*)(Bs + 2048 + wave * 512), 16, 0, 0);
        }
        __syncthreads();  // staged data visible

        bf16x8 a[4], b[4];
#pragma unroll
        for (int rt = 0; rt < 4; ++rt)
            a[rt] = *(const bf16x8*)(As + (wr * 64 + rt * 16 + colid) * 32 + quad * 8);
#pragma unroll
        for (int ct = 0; ct < 4; ++ct)
            b[ct] = *(const bf16x8*)(Bs + (wc * 64 + ct * 16 + colid) * 32 + quad * 8);
#pragma unroll
        for (int rt = 0; rt < 4; ++rt)
#pragma unroll
            for (int ct = 0; ct < 4; ++ct)
                acc[rt][ct] = __builtin_amdgcn_mfma_f32_16x16x32_bf16(
                    a[rt], b[ct], acc[rt][ct], 0, 0, 0);
    }

    // Epilogue: C frag mapping (m89): col = lane&15, row = quad*4 + reg.
#pragma unroll
    for (int rt = 0; rt < 4; ++rt) {
        float rsum[4] = {0.f, 0.f, 0.f, 0.f};
#pragma unroll
        for (int ct = 0; ct < 4; ++ct) {
#pragma unroll
            for (int reg = 0; reg < 4; ++reg) {
                const int grow = rowBase + wr * 64 + rt * 16 + quad * 4 + reg;
                const int gcol = colBase + wc * 64 + ct * 16 + colid;
                float logit = acc[rt][ct][reg] * TEMP_INV;
                if (gcol == grow + N) logit += 1.0f;  // hard-negative weight
                if (gcol == grow) posdiag[grow] = logit;  // unique writer
                rsum[reg] += __expf(logit - CBIAS);
            }
        }
#pragma unroll
        for (int reg = 0; reg < 4; ++reg) {
            float v = rsum[reg];
            v += __shfl_xor(v, 1);
            v += __shfl_xor(v, 2);
            v += __shfl_xor(v, 4);
            v += __shfl_xor(v, 8);
            if (colid == 0) {
                const int grow = rowBase + wr * 64 + rt * 16 + quad * 4 + reg;
                atomicAdd(&rowsum[grow], v);
            }
        }
    }
}

__global__ __launch_bounds__(256) void finalize_kernel(
    const float* __restrict__ rowsum, const float* __restrict__ posdiag,
    float* __restrict__ out) {
    const int t = threadIdx.x;
    float s = 0.f;
    for (int i = t; i < N; i += 256)
        s += CBIAS + logf(rowsum[i]) - posdiag[i];
    for (int m = 32; m; m >>= 1) s += __shfl_down(s, m);
    __shared__ float red[4];
    const int lane = t & 63, wave = t >> 6;
    if (lane == 0) red[wave] = s;
    __syncthreads();
    if (t == 0) out[0] = (red[0] + red[1] + red[2] + red[3]) / (float)N;
}

extern "C" void kernel_launch(void* const* d_in, const int* in_sizes, int n_in,
                              void* d_out, int out_size, void* d_ws, size_t ws_size,
                              hipStream_t stream) {
    const float* in0 = (const float*)d_in[0];  // input   [N, D] fp32
    const float* in1 = (const float*)d_in[1];  // target  [N, D] fp32
    const float* in2 = (const float*)d_in[2];  // hardneg [N, D] fp32

    // Workspace layout:
    //   Abuf: N*D bf16        =  8 MiB
    //   Bbuf: 2N*D bf16       = 16 MiB
    //   rowsum: N fp32        = 16 KiB
    //   posdiag: N fp32       = 16 KiB
    unsigned short* Abuf = (unsigned short*)d_ws;
    unsigned short* Bbuf = (unsigned short*)((char*)d_ws + (size_t)N * D * 2);
    float* rowsum = (float*)((char*)d_ws + (size_t)N * D * 2 * 3);
    float* posdiag = rowsum + N;

    hipMemsetAsync(rowsum, 0, N * sizeof(float), stream);
    normalize_kernel<<<3 * N, 256, 0, stream>>>(in0, in1, in2, Abuf, Bbuf);
    gemm_lse_kernel<<<dim3(2 * N / 128, N / 128), 256, 0, stream>>>(
        Abuf, Bbuf, rowsum, posdiag);
    finalize_kernel<<<1, 256, 0, stream>>>(rowsum, posdiag, (float*)d_out);
}